// Round 1
// baseline (1131.689 us; speedup 1.0000x reference)
//
#include <hip/hip_runtime.h>

#define D 64

__global__ void zero_kernel(float* __restrict__ p, int n) {
    int i = blockIdx.x * blockDim.x + threadIdx.x;
    if (i < n) p[i] = 0.f;
}

__global__ void deg_kernel(const int* __restrict__ row, const int* __restrict__ col,
                           const float* __restrict__ w,
                           float* __restrict__ odeg, float* __restrict__ ideg, int E) {
    int stride = gridDim.x * blockDim.x;
    for (int e = blockIdx.x * blockDim.x + threadIdx.x; e < E; e += stride) {
        float we = w[e];
        atomicAdd(&odeg[row[e]], we);
        atomicAdd(&ideg[col[e]], we);
    }
}

__global__ void rsqrt_kernel(float* __restrict__ deg, int n) {
    int i = blockIdx.x * blockDim.x + threadIdx.x;
    if (i < n) {
        float v = deg[i];
        deg[i] = (v > 0.f) ? rsqrtf(v) : 0.f;
    }
}

__global__ void init_out_kernel(float* __restrict__ out,
                                const float* __restrict__ b_src,
                                const float* __restrict__ b_dst,
                                float alpha, int total) {
    int i = blockIdx.x * blockDim.x + threadIdx.x;
    if (i < total) {
        int o = i & (D - 1);
        out[i] = alpha * b_src[o] + (1.f - alpha) * b_dst[o];
    }
}

// y[r][o] = scale * sum_k x[r][k] * W[o][k]   (i.e. scale * x @ W^T)
__global__ void transform_kernel(const float* __restrict__ x,
                                 const float* __restrict__ W,
                                 float scale, float* __restrict__ y, int N) {
    __shared__ float Wt[D][D + 1];   // Wt[k][o] = W[o][k], padded against write conflicts
    int t = threadIdx.x;
    for (int i = t; i < D * D; i += blockDim.x) {
        int o = i >> 6, k = i & 63;
        Wt[k][o] = W[i];
    }
    __syncthreads();
    int lane = t & 63;
    int sub = t >> 6;
    int rpb = blockDim.x >> 6;   // 4 rows per block
    for (int r = blockIdx.x * rpb + sub; r < N; r += gridDim.x * rpb) {
        float xv = x[(size_t)r * D + lane];
        float acc = 0.f;
#pragma unroll
        for (int k = 0; k < D; ++k)
            acc += __shfl(xv, k) * Wt[k][lane];   // Wt[k][lane]: consecutive -> conflict-free
        y[(size_t)r * D + lane] = scale * acc;
    }
}

// One 64-lane wave per edge; lane = feature index.
// wn = w[e] * d_out[row]*d_in[col] (same for both directions).
// swap==0: out[row] += wn * y[col]   (forward aggregation)
// swap==1: out[col] += wn * y[row]   (backward aggregation)
__global__ void scatter_kernel(const int* __restrict__ row, const int* __restrict__ col,
                               const float* __restrict__ w,
                               const float* __restrict__ dro, const float* __restrict__ dci,
                               const float* __restrict__ y, float* __restrict__ out,
                               int E, int swap) {
    int lane = threadIdx.x & 63;
    int e = blockIdx.x * (blockDim.x >> 6) + (threadIdx.x >> 6);
    if (e >= E) return;
    int r = row[e], c = col[e];
    float wn = w[e] * dro[r] * dci[c];
    int s = swap ? r : c;
    int dd = swap ? c : r;
    atomicAdd(&out[(size_t)dd * D + lane], wn * y[(size_t)s * D + lane]);
}

extern "C" void kernel_launch(void* const* d_in, const int* in_sizes, int n_in,
                              void* d_out, int out_size, void* d_ws, size_t ws_size,
                              hipStream_t stream) {
    const float* x     = (const float*)d_in[0];
    const int*   ei    = (const int*)d_in[1];
    const float* w     = (const float*)d_in[2];
    const float* W_src = (const float*)d_in[3];
    const float* b_src = (const float*)d_in[4];
    const float* W_dst = (const float*)d_in[5];
    const float* b_dst = (const float*)d_in[6];
    float* out = (float*)d_out;

    const int N = in_sizes[0] / D;
    const int E = in_sizes[2];
    const int* row = ei;       // edge_index[0]
    const int* col = ei + E;   // edge_index[1]
    const float alpha = 0.5f;

    // workspace layout: out_deg[N] | in_deg[N] | y[N*D]   (~26.4 MB)
    float* odeg = (float*)d_ws;
    float* ideg = odeg + N;
    float* y    = ideg + N;

    zero_kernel<<<(2 * N + 255) / 256, 256, 0, stream>>>(odeg, 2 * N);
    deg_kernel<<<2048, 256, 0, stream>>>(row, col, w, odeg, ideg, E);
    rsqrt_kernel<<<(2 * N + 255) / 256, 256, 0, stream>>>(odeg, 2 * N);
    init_out_kernel<<<(N * D + 255) / 256, 256, 0, stream>>>(out, b_src, b_dst, alpha, N * D);

    // forward: out[row] += alpha * wn * (x @ W_src^T)[col]
    transform_kernel<<<(N + 3) / 4, 256, 0, stream>>>(x, W_src, alpha, y, N);
    scatter_kernel<<<(E + 3) / 4, 256, 0, stream>>>(row, col, w, odeg, ideg, y, out, E, 0);

    // backward: out[col] += (1-alpha) * wn * (x @ W_dst^T)[row]
    transform_kernel<<<(N + 3) / 4, 256, 0, stream>>>(x, W_dst, 1.f - alpha, y, N);
    scatter_kernel<<<(E + 3) / 4, 256, 0, stream>>>(row, col, w, odeg, ideg, y, out, E, 1);
}

// Round 2
// 857.671 us; speedup vs baseline: 1.3195x; 1.3195x over previous
//
#include <hip/hip_runtime.h>

#define D 64
#define ALPHA 0.5f

__global__ void zero_kernel(int* __restrict__ p, int n) {
    int i = blockIdx.x * blockDim.x + threadIdx.x;
    if (i < n) p[i] = 0;
}

// weighted degrees + integer histogram (cnt[0..N) = out-degree count, cnt[N..2N) = in-degree count)
__global__ void deg_hist_kernel(const int* __restrict__ row, const int* __restrict__ col,
                                const float* __restrict__ w,
                                float* __restrict__ odeg, float* __restrict__ ideg,
                                int* __restrict__ cnt, int N, int E) {
    int stride = gridDim.x * blockDim.x;
    for (int e = blockIdx.x * blockDim.x + threadIdx.x; e < E; e += stride) {
        int r = row[e], c = col[e];
        float we = w[e];
        atomicAdd(&odeg[r], we);
        atomicAdd(&ideg[c], we);
        atomicAdd(&cnt[r], 1);
        atomicAdd(&cnt[N + c], 1);
    }
}

__global__ void rsqrt_kernel(float* __restrict__ deg, int n) {
    int i = blockIdx.x * blockDim.x + threadIdx.x;
    if (i < n) {
        float v = deg[i];
        deg[i] = (v > 0.f) ? rsqrtf(v) : 0.f;
    }
}

// ---- 3-kernel exclusive scan of cnt[0..L) -> ptr[0..L], blocks of 512 ----
__global__ void scan1_kernel(const int* __restrict__ cnt, int* __restrict__ bsum, int L) {
    __shared__ int s[512];
    int t = threadIdx.x;
    int i = blockIdx.x * 512 + t;
    s[t] = (i < L) ? cnt[i] : 0;
    __syncthreads();
    for (int off = 256; off; off >>= 1) {
        if (t < off) s[t] += s[t + off];
        __syncthreads();
    }
    if (t == 0) bsum[blockIdx.x] = s[0];
}

__global__ void scan2_kernel(int* __restrict__ bsum, int nb) {
    __shared__ int s[512];
    int t = threadIdx.x;
    int v = (t < nb) ? bsum[t] : 0;
    s[t] = v;
    __syncthreads();
    for (int off = 1; off < 512; off <<= 1) {
        int u = (t >= off) ? s[t - off] : 0;
        __syncthreads();
        s[t] += u;
        __syncthreads();
    }
    if (t < nb) bsum[t] = s[t] - v;   // exclusive block offsets
}

__global__ void scan3_kernel(const int* __restrict__ cnt, const int* __restrict__ bsum,
                             int* __restrict__ ptr, int* __restrict__ fillpos,
                             int L, int total) {
    __shared__ int s[512];
    int t = threadIdx.x;
    int i = blockIdx.x * 512 + t;
    int v = (i < L) ? cnt[i] : 0;
    s[t] = v;
    __syncthreads();
    for (int off = 1; off < 512; off <<= 1) {
        int u = (t >= off) ? s[t - off] : 0;
        __syncthreads();
        s[t] += u;
        __syncthreads();
    }
    if (i < L) {
        int ex = bsum[blockIdx.x] + s[t] - v;
        ptr[i] = ex;
        fillpos[i] = ex;
    }
    if (i == 0) ptr[L] = total;
}

// place each edge in both CSR segments; wn identical for both directions
__global__ void fill_kernel(const int* __restrict__ row, const int* __restrict__ col,
                            const float* __restrict__ w,
                            const float* __restrict__ odeg, const float* __restrict__ ideg,
                            int* __restrict__ fillpos,
                            int* __restrict__ esrc, float* __restrict__ ewn,
                            int N, int E) {
    int stride = gridDim.x * blockDim.x;
    for (int e = blockIdx.x * blockDim.x + threadIdx.x; e < E; e += stride) {
        int r = row[e], c = col[e];
        float wn = w[e] * odeg[r] * ideg[c];
        int p1 = atomicAdd(&fillpos[r], 1);       // fwd: dst=r, src=c
        esrc[p1] = c; ewn[p1] = wn;
        int p2 = atomicAdd(&fillpos[N + c], 1);   // bwd: dst=c, src=r
        esrc[p2] = r; ewn[p2] = wn;
    }
}

// y = scale * x @ W^T : 64-row tile GEMM, 256 threads, 4x4 outputs/thread
__global__ void transform_kernel(const float* __restrict__ x, const float* __restrict__ W,
                                 float scale, float* __restrict__ y, int N) {
    __shared__ float xs[64][65];
    __shared__ float Wt[64][68];
    int t = threadIdx.x;
    for (int i = t; i < 4096; i += 256) {
        int o = i >> 6, k = i & 63;
        Wt[k][o] = W[i];
    }
    int r0 = blockIdx.x * 64;
    for (int i = t; i < 4096; i += 256) {
        int r = i >> 6, k = i & 63;
        int gr = r0 + r;
        xs[r][k] = (gr < N) ? x[(size_t)gr * D + k] : 0.f;
    }
    __syncthreads();
    int ro = t >> 4, co = t & 15;
    float acc[4][4] = {};
#pragma unroll 8
    for (int k = 0; k < 64; ++k) {
        float a0 = xs[ro * 4 + 0][k];
        float a1 = xs[ro * 4 + 1][k];
        float a2 = xs[ro * 4 + 2][k];
        float a3 = xs[ro * 4 + 3][k];
        float4 b = *(const float4*)&Wt[k][co * 4];
        acc[0][0] += a0 * b.x; acc[0][1] += a0 * b.y; acc[0][2] += a0 * b.z; acc[0][3] += a0 * b.w;
        acc[1][0] += a1 * b.x; acc[1][1] += a1 * b.y; acc[1][2] += a1 * b.z; acc[1][3] += a1 * b.w;
        acc[2][0] += a2 * b.x; acc[2][1] += a2 * b.y; acc[2][2] += a2 * b.z; acc[2][3] += a2 * b.w;
        acc[3][0] += a3 * b.x; acc[3][1] += a3 * b.y; acc[3][2] += a3 * b.z; acc[3][3] += a3 * b.w;
    }
#pragma unroll
    for (int i = 0; i < 4; ++i) {
        int gr = r0 + ro * 4 + i;
        if (gr < N) {
            float4 o;
            o.x = acc[i][0] * scale; o.y = acc[i][1] * scale;
            o.z = acc[i][2] * scale; o.w = acc[i][3] * scale;
            *(float4*)&y[(size_t)gr * D + co * 4] = o;
        }
    }
}

// one wave per destination node, lane = feature; no atomics
__global__ void gather_fwd_kernel(const int* __restrict__ ptr, const int* __restrict__ esrc,
                                  const float* __restrict__ ewn, const float* __restrict__ y,
                                  const float* __restrict__ b_src, const float* __restrict__ b_dst,
                                  float* __restrict__ out, int N) {
    int lane = threadIdx.x & 63;
    int node = blockIdx.x * (blockDim.x >> 6) + (threadIdx.x >> 6);
    if (node >= N) return;
    float acc = ALPHA * b_src[lane] + (1.f - ALPHA) * b_dst[lane];
    int e0 = ptr[node], e1 = ptr[node + 1];
    for (int e = e0; e < e1; ++e) {
        int s = esrc[e];
        float wn = ewn[e];
        acc += wn * y[(size_t)s * D + lane];
    }
    out[(size_t)node * D + lane] = acc;
}

__global__ void gather_bwd_kernel(const int* __restrict__ ptr, const int* __restrict__ esrc,
                                  const float* __restrict__ ewn, const float* __restrict__ y,
                                  float* __restrict__ out, int N) {
    int lane = threadIdx.x & 63;
    int node = blockIdx.x * (blockDim.x >> 6) + (threadIdx.x >> 6);
    if (node >= N) return;
    float acc = 0.f;
    int e0 = ptr[N + node], e1 = ptr[N + node + 1];
    for (int e = e0; e < e1; ++e) {
        int s = esrc[e];
        float wn = ewn[e];
        acc += wn * y[(size_t)s * D + lane];
    }
    out[(size_t)node * D + lane] += acc;
}

extern "C" void kernel_launch(void* const* d_in, const int* in_sizes, int n_in,
                              void* d_out, int out_size, void* d_ws, size_t ws_size,
                              hipStream_t stream) {
    const float* x     = (const float*)d_in[0];
    const int*   ei    = (const int*)d_in[1];
    const float* w     = (const float*)d_in[2];
    const float* W_src = (const float*)d_in[3];
    const float* b_src = (const float*)d_in[4];
    const float* W_dst = (const float*)d_in[5];
    const float* b_dst = (const float*)d_in[6];
    float* out = (float*)d_out;

    const int N = in_sizes[0] / D;
    const int E = in_sizes[2];
    const int* row = ei;
    const int* col = ei + E;
    const int L = 2 * N;                 // concatenated [out-counts, in-counts]
    const int NB = (L + 511) / 512;      // scan blocks (391 for N=100k, fits 512)

    // workspace layout (4-byte words)
    float* odeg   = (float*)d_ws;                         // N
    float* ideg   = odeg + N;                             // N
    int*   cnt    = (int*)(ideg + N);                     // 2N
    int*   ptr    = cnt + L;                              // 2N+1
    int*   fillpos= ptr + L + 1;                          // 2N
    int*   bsum   = fillpos + L;                          // <=1024
    size_t off    = (size_t)8 * N + 1025 + 1024;
    off = (off + 3) & ~(size_t)3;                         // 16B align for float4
    float* y      = (float*)d_ws + off;                   // N*64
    int*   esrc   = (int*)(y + (size_t)N * D);            // 2E
    float* ewn    = (float*)(esrc + (size_t)2 * E);       // 2E

    // 1. zero degrees + counts (contiguous 4N words)
    zero_kernel<<<(4 * N + 255) / 256, 256, 0, stream>>>((int*)d_ws, 4 * N);
    // 2. degrees + histogram
    deg_hist_kernel<<<2048, 256, 0, stream>>>(row, col, w, odeg, ideg, cnt, N, E);
    // 3. d^-1/2
    rsqrt_kernel<<<(L + 255) / 256, 256, 0, stream>>>(odeg, L);
    // 4. exclusive scan cnt -> ptr (and fillpos copy)
    scan1_kernel<<<NB, 512, 0, stream>>>(cnt, bsum, L);
    scan2_kernel<<<1, 512, 0, stream>>>(bsum, NB);
    scan3_kernel<<<NB, 512, 0, stream>>>(cnt, bsum, ptr, fillpos, L, 2 * E);
    // 5. fill CSR edge lists (both directions share wn)
    fill_kernel<<<2048, 256, 0, stream>>>(row, col, w, odeg, ideg, fillpos, esrc, ewn, N, E);

    // 6. forward: out = bias + alpha * gather(adj_norm, x @ W_src^T)
    transform_kernel<<<(N + 63) / 64, 256, 0, stream>>>(x, W_src, ALPHA, y, N);
    gather_fwd_kernel<<<(N + 3) / 4, 256, 0, stream>>>(ptr, esrc, ewn, y, b_src, b_dst, out, N);

    // 7. backward: out += (1-alpha) * gather(adj_t_norm, x @ W_dst^T)
    transform_kernel<<<(N + 63) / 64, 256, 0, stream>>>(x, W_dst, 1.f - ALPHA, y, N);
    gather_bwd_kernel<<<(N + 3) / 4, 256, 0, stream>>>(ptr, esrc, ewn, y, out, N);
}

// Round 3
// 599.794 us; speedup vs baseline: 1.8868x; 1.4299x over previous
//
#include <hip/hip_runtime.h>

#define D 64
#define ALPHA 0.5f
#define FXSCALE 16777216.f   // 2^24 fixed-point quantum for degree accumulation

typedef unsigned long long u64;

__global__ void zero4_kernel(int4* __restrict__ p, int n4) {
    int i = blockIdx.x * blockDim.x + threadIdx.x;
    if (i < n4) p[i] = make_int4(0, 0, 0, 0);
}

// one packed 64-bit atomic per (edge, side): hi32 = count, lo32 = sum(w * 2^24)
__global__ void deg_hist_kernel(const int* __restrict__ row, const int* __restrict__ col,
                                const float* __restrict__ w,
                                u64* __restrict__ pk, int N, int E) {
    int stride = gridDim.x * blockDim.x;
    for (int e = blockIdx.x * blockDim.x + threadIdx.x; e < E; e += stride) {
        int r = row[e], c = col[e];
        u64 v = (1ULL << 32) | (u64)__float2uint_rn(w[e] * FXSCALE);
        atomicAdd(&pk[r], v);
        atomicAdd(&pk[N + c], v);
    }
}

// dinv[i] = deg^-1/2 (0 if empty) from packed fixed-point sum
__global__ void unpack_kernel(const u64* __restrict__ pk, float* __restrict__ dinv, int L) {
    int i = blockIdx.x * blockDim.x + threadIdx.x;
    if (i < L) {
        float s = (float)(unsigned int)(pk[i] & 0xffffffffULL) * (1.f / FXSCALE);
        dinv[i] = (s > 0.f) ? rsqrtf(s) : 0.f;
    }
}

// ---- 3-kernel exclusive scan of counts (pk >> 32) -> ptr[0..L], blocks of 512 ----
__global__ void scan1_kernel(const u64* __restrict__ pk, int* __restrict__ bsum, int L) {
    __shared__ int s[512];
    int t = threadIdx.x;
    int i = blockIdx.x * 512 + t;
    s[t] = (i < L) ? (int)(pk[i] >> 32) : 0;
    __syncthreads();
    for (int off = 256; off; off >>= 1) {
        if (t < off) s[t] += s[t + off];
        __syncthreads();
    }
    if (t == 0) bsum[blockIdx.x] = s[0];
}

__global__ void scan2_kernel(int* __restrict__ bsum, int nb) {
    __shared__ int s[512];
    int t = threadIdx.x;
    int v = (t < nb) ? bsum[t] : 0;
    s[t] = v;
    __syncthreads();
    for (int off = 1; off < 512; off <<= 1) {
        int u = (t >= off) ? s[t - off] : 0;
        __syncthreads();
        s[t] += u;
        __syncthreads();
    }
    if (t < nb) bsum[t] = s[t] - v;   // exclusive block offsets
}

__global__ void scan3_kernel(const u64* __restrict__ pk, const int* __restrict__ bsum,
                             int* __restrict__ ptr, int* __restrict__ fillpos,
                             int L, int total) {
    __shared__ int s[512];
    int t = threadIdx.x;
    int i = blockIdx.x * 512 + t;
    int v = (i < L) ? (int)(pk[i] >> 32) : 0;
    s[t] = v;
    __syncthreads();
    for (int off = 1; off < 512; off <<= 1) {
        int u = (t >= off) ? s[t - off] : 0;
        __syncthreads();
        s[t] += u;
        __syncthreads();
    }
    if (i < L) {
        int ex = bsum[blockIdx.x] + s[t] - v;
        ptr[i] = ex;
        fillpos[i] = ex;
    }
    if (i == 0) ptr[L] = total;
}

// place each edge in both CSR segments; (src, wn) packed into one 8B store
__global__ void fill_kernel(const int* __restrict__ row, const int* __restrict__ col,
                            const float* __restrict__ w,
                            const float* __restrict__ dinv,
                            int* __restrict__ fillpos,
                            float2* __restrict__ edata,
                            int N, int E) {
    int stride = gridDim.x * blockDim.x;
    for (int e = blockIdx.x * blockDim.x + threadIdx.x; e < E; e += stride) {
        int r = row[e], c = col[e];
        float wn = w[e] * dinv[r] * dinv[N + c];
        int p1 = atomicAdd(&fillpos[r], 1);       // fwd: dst=r, src=c
        edata[p1] = make_float2(__int_as_float(c), wn);
        int p2 = atomicAdd(&fillpos[N + c], 1);   // bwd: dst=c, src=r
        edata[p2] = make_float2(__int_as_float(r), wn);
    }
}

// y = scale * x @ W^T : 64-row tile GEMM, 256 threads, 4x4 outputs/thread
__global__ void transform_kernel(const float* __restrict__ x, const float* __restrict__ W,
                                 float scale, float* __restrict__ y, int N) {
    __shared__ float xs[64][65];
    __shared__ float Wt[64][68];
    int t = threadIdx.x;
    for (int i = t; i < 4096; i += 256) {
        int o = i >> 6, k = i & 63;
        Wt[k][o] = W[i];
    }
    int r0 = blockIdx.x * 64;
    for (int i = t; i < 4096; i += 256) {
        int r = i >> 6, k = i & 63;
        int gr = r0 + r;
        xs[r][k] = (gr < N) ? x[(size_t)gr * D + k] : 0.f;
    }
    __syncthreads();
    int ro = t >> 4, co = t & 15;
    float acc[4][4] = {};
#pragma unroll 8
    for (int k = 0; k < 64; ++k) {
        float a0 = xs[ro * 4 + 0][k];
        float a1 = xs[ro * 4 + 1][k];
        float a2 = xs[ro * 4 + 2][k];
        float a3 = xs[ro * 4 + 3][k];
        float4 b = *(const float4*)&Wt[k][co * 4];
        acc[0][0] += a0 * b.x; acc[0][1] += a0 * b.y; acc[0][2] += a0 * b.z; acc[0][3] += a0 * b.w;
        acc[1][0] += a1 * b.x; acc[1][1] += a1 * b.y; acc[1][2] += a1 * b.z; acc[1][3] += a1 * b.w;
        acc[2][0] += a2 * b.x; acc[2][1] += a2 * b.y; acc[2][2] += a2 * b.z; acc[2][3] += a2 * b.w;
        acc[3][0] += a3 * b.x; acc[3][1] += a3 * b.y; acc[3][2] += a3 * b.z; acc[3][3] += a3 * b.w;
    }
#pragma unroll
    for (int i = 0; i < 4; ++i) {
        int gr = r0 + ro * 4 + i;
        if (gr < N) {
            float4 o;
            o.x = acc[i][0] * scale; o.y = acc[i][1] * scale;
            o.z = acc[i][2] * scale; o.w = acc[i][3] * scale;
            *(float4*)&y[(size_t)gr * D + co * 4] = o;
        }
    }
}

// one wave per destination node, lane = feature; no atomics; unroll x2
__global__ void gather_fwd_kernel(const int* __restrict__ ptr, const float2* __restrict__ ed,
                                  const float* __restrict__ y,
                                  const float* __restrict__ b_src, const float* __restrict__ b_dst,
                                  float* __restrict__ out, int N) {
    int lane = threadIdx.x & 63;
    int node = blockIdx.x * (blockDim.x >> 6) + (threadIdx.x >> 6);
    if (node >= N) return;
    int e0 = ptr[node], e1 = ptr[node + 1];
    float acc0 = ALPHA * b_src[lane] + (1.f - ALPHA) * b_dst[lane];
    float acc1 = 0.f;
    int e = e0;
    for (; e + 2 <= e1; e += 2) {
        float2 d0 = ed[e], d1 = ed[e + 1];
        acc0 += d0.y * y[(size_t)__float_as_int(d0.x) * D + lane];
        acc1 += d1.y * y[(size_t)__float_as_int(d1.x) * D + lane];
    }
    if (e < e1) {
        float2 d0 = ed[e];
        acc0 += d0.y * y[(size_t)__float_as_int(d0.x) * D + lane];
    }
    out[(size_t)node * D + lane] = acc0 + acc1;
}

__global__ void gather_bwd_kernel(const int* __restrict__ ptr, const float2* __restrict__ ed,
                                  const float* __restrict__ y,
                                  float* __restrict__ out, int N) {
    int lane = threadIdx.x & 63;
    int node = blockIdx.x * (blockDim.x >> 6) + (threadIdx.x >> 6);
    if (node >= N) return;
    int e0 = ptr[N + node], e1 = ptr[N + node + 1];
    float acc0 = 0.f, acc1 = 0.f;
    int e = e0;
    for (; e + 2 <= e1; e += 2) {
        float2 d0 = ed[e], d1 = ed[e + 1];
        acc0 += d0.y * y[(size_t)__float_as_int(d0.x) * D + lane];
        acc1 += d1.y * y[(size_t)__float_as_int(d1.x) * D + lane];
    }
    if (e < e1) {
        float2 d0 = ed[e];
        acc0 += d0.y * y[(size_t)__float_as_int(d0.x) * D + lane];
    }
    out[(size_t)node * D + lane] += acc0 + acc1;
}

extern "C" void kernel_launch(void* const* d_in, const int* in_sizes, int n_in,
                              void* d_out, int out_size, void* d_ws, size_t ws_size,
                              hipStream_t stream) {
    const float* x     = (const float*)d_in[0];
    const int*   ei    = (const int*)d_in[1];
    const float* w     = (const float*)d_in[2];
    const float* W_src = (const float*)d_in[3];
    const float* b_src = (const float*)d_in[4];
    const float* W_dst = (const float*)d_in[5];
    const float* b_dst = (const float*)d_in[6];
    float* out = (float*)d_out;

    const int N = in_sizes[0] / D;
    const int E = in_sizes[2];
    const int* row = ei;
    const int* col = ei + E;
    const int L = 2 * N;
    const int NB = (L + 511) / 512;    // 391 blocks for N=100k, fits scan2's 512

    // workspace layout
    u64*   pk      = (u64*)d_ws;                          // 2N packed (count|fxsum)
    float* dinv    = (float*)(pk + L);                    // 2N  (out d^-1/2 | in d^-1/2)
    int*   ptr     = (int*)(dinv + L);                    // 2N+1
    int*   fillpos = ptr + L + 1;                         // 2N
    int*   bsum    = fillpos + L;                         // <=512
    size_t yoff    = ((size_t)L * 8 + (size_t)L * 4 + (size_t)(L + 1) * 4
                      + (size_t)L * 4 + 512 * 4 + 15) & ~(size_t)15;
    float* y       = (float*)((char*)d_ws + yoff);        // N*64
    float2* edata  = (float2*)(y + (size_t)N * D);        // 2E * 8B

    // 1. zero packed degree/count array (2N u64 = 4N ints = N int4)
    zero4_kernel<<<(N + 255) / 256, 256, 0, stream>>>((int4*)pk, N);
    // 2. packed degrees + histogram (2 atomics/edge)
    deg_hist_kernel<<<2048, 256, 0, stream>>>(row, col, w, pk, N, E);
    // 3. d^-1/2
    unpack_kernel<<<(L + 255) / 256, 256, 0, stream>>>(pk, dinv, L);
    // 4. exclusive scan of counts -> ptr, fillpos
    scan1_kernel<<<NB, 512, 0, stream>>>(pk, bsum, L);
    scan2_kernel<<<1, 512, 0, stream>>>(bsum, NB);
    scan3_kernel<<<NB, 512, 0, stream>>>(pk, bsum, ptr, fillpos, L, 2 * E);
    // 5. fill CSR edge lists (both directions share wn), 8B packed stores
    fill_kernel<<<2048, 256, 0, stream>>>(row, col, w, dinv, fillpos, edata, N, E);

    // 6. forward: out = bias + alpha * gather(adj_norm, x @ W_src^T)
    transform_kernel<<<(N + 63) / 64, 256, 0, stream>>>(x, W_src, ALPHA, y, N);
    gather_fwd_kernel<<<(N + 3) / 4, 256, 0, stream>>>(ptr, edata, y, b_src, b_dst, out, N);

    // 7. backward: out += (1-alpha) * gather(adj_t_norm, x @ W_dst^T)
    transform_kernel<<<(N + 63) / 64, 256, 0, stream>>>(x, W_dst, 1.f - ALPHA, y, N);
    gather_bwd_kernel<<<(N + 3) / 4, 256, 0, stream>>>(ptr, edata, y, out, N);
}

// Round 4
// 438.731 us; speedup vs baseline: 2.5795x; 1.3671x over previous
//
#include <hip/hip_runtime.h>

#define D 64
#define ALPHA 0.5f
#define FXSCALE 16777216.f   // 2^24 fixed-point quantum for degree accumulation

typedef unsigned long long u64;
typedef unsigned char u8;

__global__ void zero4_kernel(int4* __restrict__ p, int n4) {
    int i = blockIdx.x * blockDim.x + threadIdx.x;
    if (i < n4) p[i] = make_int4(0, 0, 0, 0);
}

// one packed 64-bit atomic per (edge, side): hi32 = count, lo32 = sum(w * 2^24).
// The returned old count IS this edge's rank within its destination segment.
__global__ void deg_hist_rank_kernel(const int* __restrict__ row, const int* __restrict__ col,
                                     const float* __restrict__ w,
                                     u64* __restrict__ pk,
                                     u8* __restrict__ rank_f, u8* __restrict__ rank_b,
                                     int N, int E) {
    int stride = gridDim.x * blockDim.x;
    for (int e = blockIdx.x * blockDim.x + threadIdx.x; e < E; e += stride) {
        int r = row[e], c = col[e];
        u64 v = (1ULL << 32) | (u64)__float2uint_rn(w[e] * FXSCALE);
        u64 o1 = atomicAdd(&pk[r], v);
        rank_f[e] = (u8)(o1 >> 32);
        u64 o2 = atomicAdd(&pk[N + c], v);
        rank_b[e] = (u8)(o2 >> 32);
    }
}

// dinv[i] = deg^-1/2 (0 if empty) from packed fixed-point sum
__global__ void unpack_kernel(const u64* __restrict__ pk, float* __restrict__ dinv, int L) {
    int i = blockIdx.x * blockDim.x + threadIdx.x;
    if (i < L) {
        float s = (float)(unsigned int)(pk[i] & 0xffffffffULL) * (1.f / FXSCALE);
        dinv[i] = (s > 0.f) ? rsqrtf(s) : 0.f;
    }
}

// ---- 3-kernel exclusive scan of counts (pk >> 32) -> ptr[0..L], blocks of 512 ----
__global__ void scan1_kernel(const u64* __restrict__ pk, int* __restrict__ bsum, int L) {
    __shared__ int s[512];
    int t = threadIdx.x;
    int i = blockIdx.x * 512 + t;
    s[t] = (i < L) ? (int)(pk[i] >> 32) : 0;
    __syncthreads();
    for (int off = 256; off; off >>= 1) {
        if (t < off) s[t] += s[t + off];
        __syncthreads();
    }
    if (t == 0) bsum[blockIdx.x] = s[0];
}

__global__ void scan2_kernel(int* __restrict__ bsum, int nb) {
    __shared__ int s[512];
    int t = threadIdx.x;
    int v = (t < nb) ? bsum[t] : 0;
    s[t] = v;
    __syncthreads();
    for (int off = 1; off < 512; off <<= 1) {
        int u = (t >= off) ? s[t - off] : 0;
        __syncthreads();
        s[t] += u;
        __syncthreads();
    }
    if (t < nb) bsum[t] = s[t] - v;   // exclusive block offsets
}

__global__ void scan3_kernel(const u64* __restrict__ pk, const int* __restrict__ bsum,
                             int* __restrict__ ptr, int L, int total) {
    __shared__ int s[512];
    int t = threadIdx.x;
    int i = blockIdx.x * 512 + t;
    int v = (i < L) ? (int)(pk[i] >> 32) : 0;
    s[t] = v;
    __syncthreads();
    for (int off = 1; off < 512; off <<= 1) {
        int u = (t >= off) ? s[t - off] : 0;
        __syncthreads();
        s[t] += u;
        __syncthreads();
    }
    if (i < L) ptr[i] = bsum[blockIdx.x] + s[t] - v;
    if (i == 0) ptr[L] = total;
}

// place each edge in both CSR segments at ptr[dst] + captured rank — NO atomics
__global__ void fill_ranked_kernel(const int* __restrict__ row, const int* __restrict__ col,
                                   const float* __restrict__ w,
                                   const float* __restrict__ dinv,
                                   const u8* __restrict__ rank_f, const u8* __restrict__ rank_b,
                                   const int* __restrict__ ptr,
                                   float2* __restrict__ edata,
                                   int N, int E) {
    int e = blockIdx.x * blockDim.x + threadIdx.x;
    if (e >= E) return;
    int r = row[e], c = col[e];
    float wn = w[e] * dinv[r] * dinv[N + c];
    int p1 = ptr[r] + rank_f[e];         // fwd: dst=r, src=c
    edata[p1] = make_float2(__int_as_float(c), wn);
    int p2 = ptr[N + c] + rank_b[e];     // bwd: dst=c, src=r
    edata[p2] = make_float2(__int_as_float(r), wn);
}

// fused: y1 = ALPHA * x @ Ws^T, y2 = (1-ALPHA) * x @ Wd^T (one pass over x)
__global__ void transform2_kernel(const float* __restrict__ x,
                                  const float* __restrict__ Ws, const float* __restrict__ Wd,
                                  float* __restrict__ y1, float* __restrict__ y2, int N) {
    __shared__ float xs[64][65];
    __shared__ float Wt1[64][68];
    __shared__ float Wt2[64][68];
    int t = threadIdx.x;
    for (int i = t; i < 4096; i += 256) {
        int o = i >> 6, k = i & 63;
        Wt1[k][o] = Ws[i];
        Wt2[k][o] = Wd[i];
    }
    int r0 = blockIdx.x * 64;
    for (int i = t; i < 4096; i += 256) {
        int r = i >> 6, k = i & 63;
        int gr = r0 + r;
        xs[r][k] = (gr < N) ? x[(size_t)gr * D + k] : 0.f;
    }
    __syncthreads();
    int ro = t >> 4, co = t & 15;
    float a1[4][4] = {}, a2[4][4] = {};
#pragma unroll 4
    for (int k = 0; k < 64; ++k) {
        float v0 = xs[ro * 4 + 0][k];
        float v1 = xs[ro * 4 + 1][k];
        float v2 = xs[ro * 4 + 2][k];
        float v3 = xs[ro * 4 + 3][k];
        float4 b1 = *(const float4*)&Wt1[k][co * 4];
        float4 b2 = *(const float4*)&Wt2[k][co * 4];
        a1[0][0] += v0 * b1.x; a1[0][1] += v0 * b1.y; a1[0][2] += v0 * b1.z; a1[0][3] += v0 * b1.w;
        a1[1][0] += v1 * b1.x; a1[1][1] += v1 * b1.y; a1[1][2] += v1 * b1.z; a1[1][3] += v1 * b1.w;
        a1[2][0] += v2 * b1.x; a1[2][1] += v2 * b1.y; a1[2][2] += v2 * b1.z; a1[2][3] += v2 * b1.w;
        a1[3][0] += v3 * b1.x; a1[3][1] += v3 * b1.y; a1[3][2] += v3 * b1.z; a1[3][3] += v3 * b1.w;
        a2[0][0] += v0 * b2.x; a2[0][1] += v0 * b2.y; a2[0][2] += v0 * b2.z; a2[0][3] += v0 * b2.w;
        a2[1][0] += v1 * b2.x; a2[1][1] += v1 * b2.y; a2[1][2] += v1 * b2.z; a2[1][3] += v1 * b2.w;
        a2[2][0] += v2 * b2.x; a2[2][1] += v2 * b2.y; a2[2][2] += v2 * b2.z; a2[2][3] += v2 * b2.w;
        a2[3][0] += v3 * b2.x; a2[3][1] += v3 * b2.y; a2[3][2] += v3 * b2.z; a2[3][3] += v3 * b2.w;
    }
#pragma unroll
    for (int i = 0; i < 4; ++i) {
        int gr = r0 + ro * 4 + i;
        if (gr < N) {
            float4 o1, o2;
            o1.x = a1[i][0] * ALPHA; o1.y = a1[i][1] * ALPHA;
            o1.z = a1[i][2] * ALPHA; o1.w = a1[i][3] * ALPHA;
            o2.x = a2[i][0] * (1.f - ALPHA); o2.y = a2[i][1] * (1.f - ALPHA);
            o2.z = a2[i][2] * (1.f - ALPHA); o2.w = a2[i][3] * (1.f - ALPHA);
            *(float4*)&y1[(size_t)gr * D + co * 4] = o1;
            *(float4*)&y2[(size_t)gr * D + co * 4] = o2;
        }
    }
}

// single-y transform (fallback path)
__global__ void transform_kernel(const float* __restrict__ x, const float* __restrict__ W,
                                 float scale, float* __restrict__ y, int N) {
    __shared__ float xs[64][65];
    __shared__ float Wt[64][68];
    int t = threadIdx.x;
    for (int i = t; i < 4096; i += 256) {
        int o = i >> 6, k = i & 63;
        Wt[k][o] = W[i];
    }
    int r0 = blockIdx.x * 64;
    for (int i = t; i < 4096; i += 256) {
        int r = i >> 6, k = i & 63;
        int gr = r0 + r;
        xs[r][k] = (gr < N) ? x[(size_t)gr * D + k] : 0.f;
    }
    __syncthreads();
    int ro = t >> 4, co = t & 15;
    float acc[4][4] = {};
#pragma unroll 8
    for (int k = 0; k < 64; ++k) {
        float v0 = xs[ro * 4 + 0][k];
        float v1 = xs[ro * 4 + 1][k];
        float v2 = xs[ro * 4 + 2][k];
        float v3 = xs[ro * 4 + 3][k];
        float4 b = *(const float4*)&Wt[k][co * 4];
        acc[0][0] += v0 * b.x; acc[0][1] += v0 * b.y; acc[0][2] += v0 * b.z; acc[0][3] += v0 * b.w;
        acc[1][0] += v1 * b.x; acc[1][1] += v1 * b.y; acc[1][2] += v1 * b.z; acc[1][3] += v1 * b.w;
        acc[2][0] += v2 * b.x; acc[2][1] += v2 * b.y; acc[2][2] += v2 * b.z; acc[2][3] += v2 * b.w;
        acc[3][0] += v3 * b.x; acc[3][1] += v3 * b.y; acc[3][2] += v3 * b.z; acc[3][3] += v3 * b.w;
    }
#pragma unroll
    for (int i = 0; i < 4; ++i) {
        int gr = r0 + ro * 4 + i;
        if (gr < N) {
            float4 o;
            o.x = acc[i][0] * scale; o.y = acc[i][1] * scale;
            o.z = acc[i][2] * scale; o.w = acc[i][3] * scale;
            *(float4*)&y[(size_t)gr * D + co * 4] = o;
        }
    }
}

// one wave per node: bias + fwd segment (y1) + bwd segment (y2), single out write
__global__ void gather_merged_kernel(const int* __restrict__ ptr, const float2* __restrict__ ed,
                                     const float* __restrict__ y1, const float* __restrict__ y2,
                                     const float* __restrict__ b_src, const float* __restrict__ b_dst,
                                     float* __restrict__ out, int N) {
    int lane = threadIdx.x & 63;
    int node = blockIdx.x * (blockDim.x >> 6) + (threadIdx.x >> 6);
    if (node >= N) return;
    float acc0 = ALPHA * b_src[lane] + (1.f - ALPHA) * b_dst[lane];
    float acc1 = 0.f;
    int e0 = ptr[node], e1 = ptr[node + 1];
    int e = e0;
    for (; e + 2 <= e1; e += 2) {
        float2 d0 = ed[e], d1 = ed[e + 1];
        acc0 += d0.y * y1[(size_t)__float_as_int(d0.x) * D + lane];
        acc1 += d1.y * y1[(size_t)__float_as_int(d1.x) * D + lane];
    }
    if (e < e1) {
        float2 d0 = ed[e];
        acc0 += d0.y * y1[(size_t)__float_as_int(d0.x) * D + lane];
    }
    e0 = ptr[N + node]; e1 = ptr[N + node + 1];
    for (e = e0; e + 2 <= e1; e += 2) {
        float2 d0 = ed[e], d1 = ed[e + 1];
        acc0 += d0.y * y2[(size_t)__float_as_int(d0.x) * D + lane];
        acc1 += d1.y * y2[(size_t)__float_as_int(d1.x) * D + lane];
    }
    if (e < e1) {
        float2 d0 = ed[e];
        acc0 += d0.y * y2[(size_t)__float_as_int(d0.x) * D + lane];
    }
    out[(size_t)node * D + lane] = acc0 + acc1;
}

// fallback pair (small workspace): fwd writes bias+agg, bwd RMW-adds
__global__ void gather_fwd_kernel(const int* __restrict__ ptr, const float2* __restrict__ ed,
                                  const float* __restrict__ y,
                                  const float* __restrict__ b_src, const float* __restrict__ b_dst,
                                  float* __restrict__ out, int N) {
    int lane = threadIdx.x & 63;
    int node = blockIdx.x * (blockDim.x >> 6) + (threadIdx.x >> 6);
    if (node >= N) return;
    float acc0 = ALPHA * b_src[lane] + (1.f - ALPHA) * b_dst[lane];
    float acc1 = 0.f;
    int e0 = ptr[node], e1 = ptr[node + 1];
    int e = e0;
    for (; e + 2 <= e1; e += 2) {
        float2 d0 = ed[e], d1 = ed[e + 1];
        acc0 += d0.y * y[(size_t)__float_as_int(d0.x) * D + lane];
        acc1 += d1.y * y[(size_t)__float_as_int(d1.x) * D + lane];
    }
    if (e < e1) {
        float2 d0 = ed[e];
        acc0 += d0.y * y[(size_t)__float_as_int(d0.x) * D + lane];
    }
    out[(size_t)node * D + lane] = acc0 + acc1;
}

__global__ void gather_bwd_kernel(const int* __restrict__ ptr, const float2* __restrict__ ed,
                                  const float* __restrict__ y,
                                  float* __restrict__ out, int N) {
    int lane = threadIdx.x & 63;
    int node = blockIdx.x * (blockDim.x >> 6) + (threadIdx.x >> 6);
    if (node >= N) return;
    float acc0 = 0.f, acc1 = 0.f;
    int e0 = ptr[N + node], e1 = ptr[N + node + 1];
    int e = e0;
    for (; e + 2 <= e1; e += 2) {
        float2 d0 = ed[e], d1 = ed[e + 1];
        acc0 += d0.y * y[(size_t)__float_as_int(d0.x) * D + lane];
        acc1 += d1.y * y[(size_t)__float_as_int(d1.x) * D + lane];
    }
    if (e < e1) {
        float2 d0 = ed[e];
        acc0 += d0.y * y[(size_t)__float_as_int(d0.x) * D + lane];
    }
    out[(size_t)node * D + lane] += acc0 + acc1;
}

extern "C" void kernel_launch(void* const* d_in, const int* in_sizes, int n_in,
                              void* d_out, int out_size, void* d_ws, size_t ws_size,
                              hipStream_t stream) {
    const float* x     = (const float*)d_in[0];
    const int*   ei    = (const int*)d_in[1];
    const float* w     = (const float*)d_in[2];
    const float* W_src = (const float*)d_in[3];
    const float* b_src = (const float*)d_in[4];
    const float* W_dst = (const float*)d_in[5];
    const float* b_dst = (const float*)d_in[6];
    float* out = (float*)d_out;

    const int N = in_sizes[0] / D;
    const int E = in_sizes[2];
    const int* row = ei;
    const int* col = ei + E;
    const int L = 2 * N;
    const int NB = (L + 511) / 512;    // 391 for N=100k, fits scan2's 512

    // workspace layout (16B-aligned chunks)
    char* base = (char*)d_ws;
    size_t off = 0;
    auto take = [&](size_t bytes) { char* p = base + off; off = (off + bytes + 15) & ~(size_t)15; return p; };
    u64*   pk     = (u64*)take((size_t)L * 8);
    float* dinv   = (float*)take((size_t)L * 4);
    int*   ptr    = (int*)take((size_t)(L + 1) * 4);
    int*   bsum   = (int*)take(512 * 4);
    u8*    rank_f = (u8*)take((size_t)E);
    u8*    rank_b = (u8*)take((size_t)E);
    float* y1     = (float*)take((size_t)N * D * 4);
    float2* edata = (float2*)take((size_t)2 * E * 8);
    size_t need_big = off + (size_t)N * D * 4;
    float* y2     = (float*)(base + off);             // only used if it fits
    bool big = (need_big <= ws_size);

    // 1. zero packed degree/count array (2N u64 = N int4)
    zero4_kernel<<<(N + 255) / 256, 256, 0, stream>>>((int4*)pk, N);
    // 2. packed degrees + histogram, capturing per-edge ranks from atomic returns
    deg_hist_rank_kernel<<<2048, 256, 0, stream>>>(row, col, w, pk, rank_f, rank_b, N, E);
    // 3. d^-1/2
    unpack_kernel<<<(L + 255) / 256, 256, 0, stream>>>(pk, dinv, L);
    // 4. exclusive scan of counts -> ptr
    scan1_kernel<<<NB, 512, 0, stream>>>(pk, bsum, L);
    scan2_kernel<<<1, 512, 0, stream>>>(bsum, NB);
    scan3_kernel<<<NB, 512, 0, stream>>>(pk, bsum, ptr, L, 2 * E);
    // 5. fill CSR edge lists via ptr+rank (atomic-free)
    fill_ranked_kernel<<<(E + 255) / 256, 256, 0, stream>>>(row, col, w, dinv, rank_f, rank_b,
                                                            ptr, edata, N, E);

    if (big) {
        // 6. both transforms in one pass, then one merged gather (single out write)
        transform2_kernel<<<(N + 63) / 64, 256, 0, stream>>>(x, W_src, W_dst, y1, y2, N);
        gather_merged_kernel<<<(N + 3) / 4, 256, 0, stream>>>(ptr, edata, y1, y2,
                                                              b_src, b_dst, out, N);
    } else {
        transform_kernel<<<(N + 63) / 64, 256, 0, stream>>>(x, W_src, ALPHA, y1, N);
        gather_fwd_kernel<<<(N + 3) / 4, 256, 0, stream>>>(ptr, edata, y1, b_src, b_dst, out, N);
        transform_kernel<<<(N + 63) / 64, 256, 0, stream>>>(x, W_dst, 1.f - ALPHA, y1, N);
        gather_bwd_kernel<<<(N + 3) / 4, 256, 0, stream>>>(ptr, edata, y1, out, N);
    }
}